// Round 2
// baseline (882.541 us; speedup 1.0000x reference)
//
#include <hip/hip_runtime.h>

// Problem: SHAPE = (L=4, B=64, H=512, W=512), fp32.
// diff[i,j] = sum_{H,W}(amax - aorg);  out = sum_i mean_j 10*exp(-diff)
// Memory-bound: 512 MiB read once -> ~85 us floor at 6.3 TB/s achievable.
//
// R5: identical to R4 (bench infra flaked — "container failed twice", no
// signal). R4 rationale: fuse the finalize into the main kernel
// (last-block-done pattern). rocprof R3 showed both our kernels < 158 us
// (absent from top-5, which is all 160-us harness poison fills at 6.7 TB/s);
// the remaining controllable cost is dispatch structure, not the load loop.
// Load loop kept IDENTICAL to R3 (16B/lane nt loads, 4-chain acc, 32
// blocks/slice) as a single-variable experiment. Per-slice device-scope
// atomicAdd (8192 adds / 256 addrs), release-fence + ticket counter, last
// block computes the exp/mean/sum inline. 1 KiB memsetAsync re-zeros
// accumulators+counter each launch (graph-capturable; counter reset per
// iteration is load-bearing).

typedef float v4f __attribute__((ext_vector_type(4)));

#define L_DIM 4
#define B_DIM 64
#define HW (512 * 512)                     // 262144 elems per slice, contiguous
#define SLICES (L_DIM * B_DIM)             // 256
#define BLOCKS_PER_SLICE 32
#define GRID (SLICES * BLOCKS_PER_SLICE)   // 8192 blocks
#define THREADS 256
#define CHUNK (HW / BLOCKS_PER_SLICE)      // 8192 elems per block
#define VPT (CHUNK / THREADS / 4)          // 8 v4f loads per thread per input

__global__ __launch_bounds__(THREADS) void ra_fused_kernel(
    const float* __restrict__ amax, const float* __restrict__ aorg,
    float* __restrict__ slice_sum, unsigned* __restrict__ counter,
    float* __restrict__ out) {
  const int bid = blockIdx.x;                   // 0..8191
  const int slice = bid >> 5;                   // bid / BLOCKS_PER_SLICE
  const int sub = bid & (BLOCKS_PER_SLICE - 1);
  const size_t base = (size_t)slice * HW + (size_t)sub * CHUNK;
  const v4f* pm = (const v4f*)(amax + base);
  const v4f* po = (const v4f*)(aorg + base);
  const int t = threadIdx.x;

  v4f a = {0.f, 0.f, 0.f, 0.f};                 // 4 independent FP chains
#pragma unroll
  for (int k = 0; k < VPT; ++k) {
    v4f m = __builtin_nontemporal_load(&pm[k * THREADS + t]);  // 16B/lane coalesced
    v4f o = __builtin_nontemporal_load(&po[k * THREADS + t]);
    a += m - o;
  }
  float acc = (a.x + a.y) + (a.z + a.w);

  // wave-64 shuffle reduction
#pragma unroll
  for (int off = 32; off > 0; off >>= 1) acc += __shfl_down(acc, off, 64);

  __shared__ float smem[THREADS / 64];
  __shared__ int is_last;
  const int lane = t & 63, wave = t >> 6;
  if (lane == 0) smem[wave] = acc;
  __syncthreads();

  if (t == 0) {
    float block_sum = smem[0] + smem[1] + smem[2] + smem[3];
    atomicAdd(&slice_sum[slice], block_sum);    // device-scope by default (m20)
    __threadfence();                            // release slice_sum before ticket
    unsigned ticket = atomicAdd(counter, 1u);   // acquire point for last block
    is_last = (ticket == GRID - 1);
  }
  __syncthreads();                              // broadcast is_last (block-uniform)

  if (is_last) {
    // Finalize: 256 threads, one slice each. Agent-scope load bypasses L1 so
    // we read the coherent values produced by the device-scope atomics.
    float diff = __hip_atomic_load(&slice_sum[t], __ATOMIC_RELAXED,
                                   __HIP_MEMORY_SCOPE_AGENT);
    float v = 10.0f * __expf(-diff) * (1.0f / B_DIM);  // mean over j folded in
    // diff is O(1); fast-exp rel err ~1e-5 on O(10) output vs 0.815 threshold: safe.
#pragma unroll
    for (int off = 32; off > 0; off >>= 1) v += __shfl_down(v, off, 64);
    if (lane == 0) smem[wave] = v;              // smem reads all happened pre-barrier
    __syncthreads();
    if (t == 0) out[0] = smem[0] + smem[1] + smem[2] + smem[3];
  }
}

extern "C" void kernel_launch(void* const* d_in, const int* in_sizes, int n_in,
                              void* d_out, int out_size, void* d_ws, size_t ws_size,
                              hipStream_t stream) {
  const float* amax = (const float*)d_in[0];
  const float* aorg = (const float*)d_in[1];
  float* out = (float*)d_out;
  float* slice_sum = (float*)d_ws;                       // 256 floats
  unsigned* counter = (unsigned*)d_ws + SLICES;          // 1 uint

  // Zero accumulators + ticket counter (1028 B). Must run every launch.
  hipMemsetAsync(d_ws, 0, (SLICES + 1) * sizeof(float), stream);
  ra_fused_kernel<<<GRID, THREADS, 0, stream>>>(amax, aorg, slice_sum, counter, out);
}

// Round 3
// 511.223 us; speedup vs baseline: 1.7263x; 1.7263x over previous
//
#include <hip/hip_runtime.h>

// Problem: SHAPE = (L=4, B=64, H=512, W=512), fp32.
// diff[i,j] = sum_{H,W}(amax - aorg);  out = sum_i mean_j 10*exp(-diff)
// Memory-bound: 512 MiB read once -> ~85 us floor at 6.3 TB/s achievable.
//
// R6: R5 post-mortem — fused kernel ran 497 us @ 541 GB/s (6.8% peak),
// VALUBusy 1.2%, occupancy 85%: memory system crawling, not latency-starved.
// Cause: __threadfence() (device-scope seq_cst) lowers on gfx950 to
// s_waitcnt + buffer_wbl2 sc1 + buffer_inv sc1 -- a full per-XCD L2
// writeback+invalidate, executed by EVERY one of 8192 blocks => constant L2
// flash-invalidation storm, streaming reads can't cache, TCC drains.
// Fix: both slice_sum and counter are device-scope atomics (performed at the
// coherence point); the only ordering required is "my slice_sum add completed
// before my ticket increment" == s_waitcnt vmcnt(0). No cache maintenance.
// Last block reads slice_sum via agent-scope atomic load (bypasses L1/L2).
// Load loop remains IDENTICAL to R3 (16B/lane nt loads, 4-chain acc,
// 32 blocks/slice, 256 threads).

typedef float v4f __attribute__((ext_vector_type(4)));

#define L_DIM 4
#define B_DIM 64
#define HW (512 * 512)                     // 262144 elems per slice, contiguous
#define SLICES (L_DIM * B_DIM)             // 256
#define BLOCKS_PER_SLICE 32
#define GRID (SLICES * BLOCKS_PER_SLICE)   // 8192 blocks
#define THREADS 256
#define CHUNK (HW / BLOCKS_PER_SLICE)      // 8192 elems per block
#define VPT (CHUNK / THREADS / 4)          // 8 v4f loads per thread per input

__global__ __launch_bounds__(THREADS) void ra_fused_kernel(
    const float* __restrict__ amax, const float* __restrict__ aorg,
    float* __restrict__ slice_sum, unsigned* __restrict__ counter,
    float* __restrict__ out) {
  const int bid = blockIdx.x;                   // 0..8191
  const int slice = bid >> 5;                   // bid / BLOCKS_PER_SLICE
  const int sub = bid & (BLOCKS_PER_SLICE - 1);
  const size_t base = (size_t)slice * HW + (size_t)sub * CHUNK;
  const v4f* pm = (const v4f*)(amax + base);
  const v4f* po = (const v4f*)(aorg + base);
  const int t = threadIdx.x;

  v4f a = {0.f, 0.f, 0.f, 0.f};                 // 4 independent FP chains
#pragma unroll
  for (int k = 0; k < VPT; ++k) {
    v4f m = __builtin_nontemporal_load(&pm[k * THREADS + t]);  // 16B/lane coalesced
    v4f o = __builtin_nontemporal_load(&po[k * THREADS + t]);
    a += m - o;
  }
  float acc = (a.x + a.y) + (a.z + a.w);

  // wave-64 shuffle reduction
#pragma unroll
  for (int off = 32; off > 0; off >>= 1) acc += __shfl_down(acc, off, 64);

  __shared__ float smem[THREADS / 64];
  __shared__ int is_last;
  const int lane = t & 63, wave = t >> 6;
  if (lane == 0) smem[wave] = acc;
  __syncthreads();

  if (t == 0) {
    float block_sum = smem[0] + smem[1] + smem[2] + smem[3];
    atomicAdd(&slice_sum[slice], block_sum);    // device-scope, at coherence point
    // Order: slice_sum add must COMPLETE before the ticket increment.
    // s_waitcnt vmcnt(0) is sufficient (both ops are coherence-point atomics);
    // do NOT use __threadfence() -- its buffer_inv sc1 invalidates the whole
    // per-XCD L2 and cost ~3.4x kernel time in R5.
    asm volatile("s_waitcnt vmcnt(0)" ::: "memory");
    unsigned ticket = atomicAdd(counter, 1u);   // relaxed device-scope ticket
    is_last = (ticket == GRID - 1);
  }
  __syncthreads();                              // broadcast is_last (block-uniform)

  if (is_last) {
    // Finalize: 256 threads, one slice each. Agent-scope load bypasses L1/L2
    // so we read the coherent values produced by the device-scope atomics.
    float diff = __hip_atomic_load(&slice_sum[t], __ATOMIC_RELAXED,
                                   __HIP_MEMORY_SCOPE_AGENT);
    float v = 10.0f * __expf(-diff) * (1.0f / B_DIM);  // mean over j folded in
    // diff is O(1); fast-exp rel err ~1e-5 on O(10) output vs 0.815 threshold: safe.
#pragma unroll
    for (int off = 32; off > 0; off >>= 1) v += __shfl_down(v, off, 64);
    if (lane == 0) smem[wave] = v;              // smem reads all happened pre-barrier
    __syncthreads();
    if (t == 0) out[0] = smem[0] + smem[1] + smem[2] + smem[3];
  }
}

extern "C" void kernel_launch(void* const* d_in, const int* in_sizes, int n_in,
                              void* d_out, int out_size, void* d_ws, size_t ws_size,
                              hipStream_t stream) {
  const float* amax = (const float*)d_in[0];
  const float* aorg = (const float*)d_in[1];
  float* out = (float*)d_out;
  float* slice_sum = (float*)d_ws;                       // 256 floats
  unsigned* counter = (unsigned*)d_ws + SLICES;          // 1 uint

  // Zero accumulators + ticket counter (1028 B). Must run every launch.
  hipMemsetAsync(d_ws, 0, (SLICES + 1) * sizeof(float), stream);
  ra_fused_kernel<<<GRID, THREADS, 0, stream>>>(amax, aorg, slice_sum, counter, out);
}

// Round 4
// 478.451 us; speedup vs baseline: 1.8446x; 1.0685x over previous
//
#include <hip/hip_runtime.h>

// Problem: SHAPE = (L=4, B=64, H=512, W=512), fp32.
// diff[i,j] = sum_{H,W}(amax - aorg);  out = sum_i mean_j 10*exp(-diff)
// Memory-bound: 537 MB read once; ~85 us floor at 6.3 TB/s (less with LLC
// half-hits: R5 FETCH_SIZE=268MB => half the footprint comes from L3).
//
// R7: persistent-shaped grid. R6 post-mortem: fence fix confirmed (kernel
// dropped 497 -> <158 us, absent from top-5); remaining controllable cost is
// the load kernel itself. Old grid = 8192 blocks on a 2048-resident machine
// => 4 sequential block generations per CU, 4x per-block protocol cost
// (setup, wave drain, reduce, atomic). New: exactly 2048 blocks (8/CU, full
// wave occupancy at 256 thr), each covering 4x the data (32768 elems/stream,
// 128 KiB contiguous per stream), one atomic per block (2048 total).
// Load pattern per inner iter is IDENTICAL to R3/R6 (16B/lane coalesced nt
// loads, stride-256, 4-chain vector accumulator). Completion protocol
// unchanged from R6 (vmcnt(0) ordering, NO __threadfence/L2-invalidate).

typedef float v4f __attribute__((ext_vector_type(4)));

#define L_DIM 4
#define B_DIM 64
#define HW (512 * 512)                     // 262144 elems per slice, contiguous
#define SLICES (L_DIM * B_DIM)             // 256
#define BLOCKS_PER_SLICE 8
#define GRID (SLICES * BLOCKS_PER_SLICE)   // 2048 blocks == resident capacity
#define THREADS 256
#define CHUNK (HW / BLOCKS_PER_SLICE)      // 32768 elems per block per stream
#define VPT (CHUNK / THREADS / 4)          // 32 v4f loads per thread per stream

__global__ __launch_bounds__(THREADS) void ra_fused_kernel(
    const float* __restrict__ amax, const float* __restrict__ aorg,
    float* __restrict__ slice_sum, unsigned* __restrict__ counter,
    float* __restrict__ out) {
  const int bid = blockIdx.x;                   // 0..2047
  const int slice = bid >> 3;                   // bid / BLOCKS_PER_SLICE
  const int sub = bid & (BLOCKS_PER_SLICE - 1);
  const size_t base = (size_t)slice * HW + (size_t)sub * CHUNK;
  const v4f* pm = (const v4f*)(amax + base);
  const v4f* po = (const v4f*)(aorg + base);
  const int t = threadIdx.x;

  v4f a = {0.f, 0.f, 0.f, 0.f};                 // 4 independent FP chains
#pragma unroll 1
  for (int c = 0; c < VPT; c += 8) {            // 4 outer iters
#pragma unroll
    for (int k = 0; k < 8; ++k) {               // 16 x 16B loads in flight
      v4f m = __builtin_nontemporal_load(&pm[(c + k) * THREADS + t]);
      v4f o = __builtin_nontemporal_load(&po[(c + k) * THREADS + t]);
      a += m - o;
    }
  }
  float acc = (a.x + a.y) + (a.z + a.w);

  // wave-64 shuffle reduction
#pragma unroll
  for (int off = 32; off > 0; off >>= 1) acc += __shfl_down(acc, off, 64);

  __shared__ float smem[THREADS / 64];
  __shared__ int is_last;
  const int lane = t & 63, wave = t >> 6;
  if (lane == 0) smem[wave] = acc;
  __syncthreads();

  if (t == 0) {
    float block_sum = smem[0] + smem[1] + smem[2] + smem[3];
    atomicAdd(&slice_sum[slice], block_sum);    // device-scope, coherence point
    // Order: slice_sum add must COMPLETE before the ticket increment.
    // s_waitcnt vmcnt(0) suffices (both are coherence-point atomics); NOT
    // __threadfence() -- its buffer_inv sc1 flash-invalidates the per-XCD L2
    // (cost ~3.4x kernel time in R5).
    asm volatile("s_waitcnt vmcnt(0)" ::: "memory");
    unsigned ticket = atomicAdd(counter, 1u);   // relaxed device-scope ticket
    is_last = (ticket == GRID - 1);
  }
  __syncthreads();                              // broadcast is_last (block-uniform)

  if (is_last) {
    // Finalize: 256 threads, one slice each. Agent-scope load bypasses L1/L2
    // so we read the coherent values produced by the device-scope atomics.
    float diff = __hip_atomic_load(&slice_sum[t], __ATOMIC_RELAXED,
                                   __HIP_MEMORY_SCOPE_AGENT);
    float v = 10.0f * __expf(-diff) * (1.0f / B_DIM);  // mean over j folded in
    // diff is O(1); fast-exp rel err ~1e-5 on O(10) output vs 0.815 threshold: safe.
#pragma unroll
    for (int off = 32; off > 0; off >>= 1) v += __shfl_down(v, off, 64);
    if (lane == 0) smem[wave] = v;              // smem reads all happened pre-barrier
    __syncthreads();
    if (t == 0) out[0] = smem[0] + smem[1] + smem[2] + smem[3];
  }
}

extern "C" void kernel_launch(void* const* d_in, const int* in_sizes, int n_in,
                              void* d_out, int out_size, void* d_ws, size_t ws_size,
                              hipStream_t stream) {
  const float* amax = (const float*)d_in[0];
  const float* aorg = (const float*)d_in[1];
  float* out = (float*)d_out;
  float* slice_sum = (float*)d_ws;                       // 256 floats
  unsigned* counter = (unsigned*)d_ws + SLICES;          // 1 uint

  // Zero accumulators + ticket counter (1028 B). Must run every launch.
  hipMemsetAsync(d_ws, 0, (SLICES + 1) * sizeof(float), stream);
  ra_fused_kernel<<<GRID, THREADS, 0, stream>>>(amax, aorg, slice_sum, counter, out);
}